// Round 5
// baseline (27.104 us; speedup 1.0000x reference)
//
#include <hip/hip_runtime.h>
#include <math.h>

namespace {

constexpr int BATCH = 16;
constexpr int Ww = 96;
constexpr int NP = 96 * 96;      // 9216
constexpr int NHYP = 128;
constexpr int HPB = 2;           // hypotheses per block
constexpr int GPB = NHYP / HPB;  // 64 blocks per batch

__device__ inline void waveSum2D(double& a, double& b) {
#pragma unroll
  for (int o = 32; o >= 1; o >>= 1) {
    a += __shfl_xor(a, o, 64);
    b += __shfl_xor(b, o, 64);
  }
}
__device__ inline void waveSum2I(int& a, int& b) {
#pragma unroll
  for (int o = 32; o >= 1; o >>= 1) {
    a += __shfl_xor(a, o, 64);
    b += __shfl_xor(b, o, 64);
  }
}
__device__ inline double waveSumD(double v) {
#pragma unroll
  for (int o = 32; o >= 1; o >>= 1) v += __shfl_xor(v, o, 64);
  return v;
}

// One fused kernel, 1024 blocks x 256 threads. Block owns (batch b, 2 hyps).
// Phase 1 (redundant per block, bitwise-identical across blocks): f64 2x2
//   solve per hyp + batch stats (ddof=1) + one-sided z>2 outlier replacement,
//   all into LDS. No global intermediate tables.
// Phase 2: votes for the block's 2 hyps (float4 pixel loads; vote test
//   yy*u + yx*v > y*u + x*v — the reference's normalization is
//   sign-preserving; NaN compares false).
// Phase 3: fold into 3 f64 partials {sum w, sum py*w, sum px*w}; publish via
//   RELAXED/AGENT atomic stores (sc1, coherent point — NO threadfence, which
//   caused the round-2/3 L2-invalidation catastrophe); raw vmcnt(0) wait
//   orders them before the ticket atomicAdd. Last block of the batch reduces
//   the 64 slots (fixed order -> deterministic) and writes out[, ::-1].
__global__ __launch_bounds__(256, 4)
void fused_kernel(const float* __restrict__ uv, const int* __restrict__ pair,
                  double* __restrict__ partials,  // [BATCH][3][GPB]
                  int* __restrict__ done,         // [BATCH], memset 0 per call
                  float* __restrict__ out) {
  __shared__ double sPy[NHYP], sPx[NHYP];
  __shared__ float sWm[NHYP];
  __shared__ int sNan[NHYP];
  __shared__ double sh[2][2];
  __shared__ int sC[4][2];
  __shared__ int sPrev;
  __shared__ double sD[3];

  const int t = threadIdx.x;
  const int lane = t & 63;
  const int wv = t >> 6;
  const int b = blockIdx.x >> 6;         // / GPB
  const int g = blockIdx.x & (GPB - 1);
  const float* uvb = uv + (size_t)b * 2 * NP;

  // ---- phase 1: solves (threads 0..127), stats with all-wave shuffles ----
  double Yy = 0.0, Yx = 0.0;
  if (t < NHYP) {
    int i0 = pair[(b * NHYP + t) * 2 + 0];
    int i1 = pair[(b * NHYP + t) * 2 + 1];
    double u0 = uvb[i0], v0 = uvb[NP + i0];
    double u1 = uvb[i1], v1 = uvb[NP + i1];
    double y0 = (double)(i0 / Ww), x0 = (double)(i0 % Ww);
    double y1 = (double)(i1 / Ww), x1 = (double)(i1 % Ww);
    // A = [[u0,-u1],[v0,-v1]], Bvec = [y1-y0, x1-x0]; s = (A^-1 Bvec).x
    double det = u1 * v0 - u0 * v1;
    double s = (u1 * (x1 - x0) - v1 * (y1 - y0)) / det;
    Yy = s * u0 + y0;
    Yx = s * v0 + x0;
  }
  double sy = Yy, sx = Yx;
  waveSum2D(sy, sx);                       // waves 2,3 shuffle zeros: harmless
  if (lane == 0 && wv < 2) { sh[wv][0] = sy; sh[wv][1] = sx; }
  __syncthreads();
  const double my = (sh[0][0] + sh[1][0]) * (1.0 / NHYP);
  const double mx = (sh[0][1] + sh[1][1]) * (1.0 / NHYP);
  const double dy = Yy - my, dx = Yx - mx;
  double qy = dy * dy, qx = dx * dx;
  waveSum2D(qy, qx);
  __syncthreads();
  if (lane == 0 && wv < 2) { sh[wv][0] = qy; sh[wv][1] = qx; }
  __syncthreads();
  if (t < NHYP) {
    double vy = (sh[0][0] + sh[1][0]) * (1.0 / (NHYP - 1));
    double vx = (sh[0][1] + sh[1][1]) * (1.0 / (NHYP - 1));
    // dy/sqrt(vy) > 2  <=>  dy > 2*sqrt(vy)   (incl. 0/0->NaN->false, +inf)
    bool outl = (dy > 2.0 * sqrt(vy)) || (dx > 2.0 * sqrt(vx));
    double py = outl ? my : Yy;
    double px = outl ? mx : Yx;
    sPy[t] = py;
    sPx[t] = px;
    // h_in_mask==1 <=> trunc(Yp) hits a lattice point <=> Yp in (-1,96)^2
    sWm[t] = (py > -1.0 && py < 96.0 && px > -1.0 && px < 96.0) ? 10.0f : 1.0f;
    sNan[t] = (isnan(py) || isnan(px)) ? 1 : 0;
  }
  __syncthreads();

  // ---- phase 2: votes for hyps h0, h1 ----
  const int h0 = g * HPB, h1 = h0 + 1;
  const float yy0 = (float)sPy[h0], yx0 = (float)sPx[h0];
  const float yy1 = (float)sPy[h1], yx1 = (float)sPx[h1];
  int c0 = 0, c1 = 0;
#pragma unroll
  for (int it = 0; it < 9; ++it) {
    const int p = (it * 256 + t) * 4;      // 96%4==0: group stays in one row
    const float4 u4 = *(const float4*)(uvb + p);
    const float4 v4 = *(const float4*)(uvb + NP + p);
    const int yi = p / Ww;
    const float fy = (float)yi;
    const float fx = (float)(p - yi * Ww);
    const float k0 = fy * u4.x + fx * v4.x;
    const float k1 = fy * u4.y + (fx + 1.0f) * v4.y;
    const float k2 = fy * u4.z + (fx + 2.0f) * v4.z;
    const float k3 = fy * u4.w + (fx + 3.0f) * v4.w;
    c0 += (fmaf(yy0, u4.x, yx0 * v4.x) > k0) ? 1 : 0;
    c0 += (fmaf(yy0, u4.y, yx0 * v4.y) > k1) ? 1 : 0;
    c0 += (fmaf(yy0, u4.z, yx0 * v4.z) > k2) ? 1 : 0;
    c0 += (fmaf(yy0, u4.w, yx0 * v4.w) > k3) ? 1 : 0;
    c1 += (fmaf(yy1, u4.x, yx1 * v4.x) > k0) ? 1 : 0;
    c1 += (fmaf(yy1, u4.y, yx1 * v4.y) > k1) ? 1 : 0;
    c1 += (fmaf(yy1, u4.z, yx1 * v4.z) > k2) ? 1 : 0;
    c1 += (fmaf(yy1, u4.w, yx1 * v4.w) > k3) ? 1 : 0;
  }
  waveSum2I(c0, c1);
  if (lane == 0) { sC[wv][0] = c0; sC[wv][1] = c1; }
  __syncthreads();

  // ---- phase 3: publish partials + ticket ----
  if (t == 0) {
    int cnt0 = sC[0][0] + sC[1][0] + sC[2][0] + sC[3][0];
    int cnt1 = sC[0][1] + sC[1][1] + sC[2][1] + sC[3][1];
    double w0 = sNan[h0] ? 0.0 : (double)cnt0 * (double)sWm[h0];
    double w1 = sNan[h1] ? 0.0 : (double)cnt1 * (double)sWm[h1];
    double ny = (sNan[h0] ? 0.0 : sPy[h0] * w0) + (sNan[h1] ? 0.0 : sPy[h1] * w1);
    double nx = (sNan[h0] ? 0.0 : sPx[h0] * w0) + (sNan[h1] ? 0.0 : sPx[h1] * w1);
    double* slot = partials + (size_t)b * 3 * GPB;
    __hip_atomic_store(&slot[0 * GPB + g], w0 + w1, __ATOMIC_RELAXED,
                       __HIP_MEMORY_SCOPE_AGENT);
    __hip_atomic_store(&slot[1 * GPB + g], ny, __ATOMIC_RELAXED,
                       __HIP_MEMORY_SCOPE_AGENT);
    __hip_atomic_store(&slot[2 * GPB + g], nx, __ATOMIC_RELAXED,
                       __HIP_MEMORY_SCOPE_AGENT);
    // order the sc1 stores before the ticket WITHOUT cache-maintenance ops
    asm volatile("s_waitcnt vmcnt(0)" ::: "memory");
    sPrev = __hip_atomic_fetch_add(&done[b], 1, __ATOMIC_RELAXED,
                                   __HIP_MEMORY_SCOPE_AGENT);
  }
  __syncthreads();
  if (sPrev != GPB - 1) return;

  // ---- last block of batch: deterministic final reduce ----
  double val = 0.0;
  if (wv < 3)
    val = __hip_atomic_load(&partials[((size_t)b * 3 + wv) * GPB + lane],
                            __ATOMIC_RELAXED, __HIP_MEMORY_SCOPE_AGENT);
  val = waveSumD(val);
  if (lane == 0 && wv < 3) sD[wv] = val;
  __syncthreads();
  if (t == 0) {
    double wsum = sD[0];
    out[b * 2 + 0] = (float)(sD[2] / wsum);   // weighted_mean[:, ::-1]
    out[b * 2 + 1] = (float)(sD[1] / wsum);
  }
}

}  // namespace

extern "C" void kernel_launch(void* const* d_in, const int* in_sizes, int n_in,
                              void* d_out, int out_size, void* d_ws, size_t ws_size,
                              hipStream_t stream) {
  const float* uv = (const float*)d_in[0];   // (16,2,96,96) f32
  // d_in[1] = mask, unused (all ones; never read by the reference math)
  const int* pair = (const int*)d_in[2];     // (16,128,2) i32
  float* out = (float*)d_out;                // (16,2) f32

  char* ws = (char*)d_ws;
  double* partials = (double*)ws;            // 16*3*64*8 = 24576 B
  int* done = (int*)(ws + 24576);            // 16*4      =    64 B

  hipMemsetAsync(done, 0, BATCH * sizeof(int), stream);
  fused_kernel<<<BATCH * GPB, 256, 0, stream>>>(uv, pair, partials, done, out);
}

// Round 6
// 15.089 us; speedup vs baseline: 1.7963x; 1.7963x over previous
//
#include <hip/hip_runtime.h>
#include <math.h>

namespace {

constexpr int BATCH = 16;
constexpr int Ww = 96;
constexpr int NP = 96 * 96;      // 9216
constexpr int NHYP = 128;
constexpr int HPB = 2;           // hypotheses per block
constexpr int GPB = NHYP / HPB;  // 64 blocks per batch

__device__ inline void waveSum2D(double& a, double& b) {
#pragma unroll
  for (int o = 32; o >= 1; o >>= 1) {
    a += __shfl_xor(a, o, 64);
    b += __shfl_xor(b, o, 64);
  }
}
__device__ inline void waveSum2I(int& a, int& b) {
#pragma unroll
  for (int o = 32; o >= 1; o >>= 1) {
    a += __shfl_xor(a, o, 64);
    b += __shfl_xor(b, o, 64);
  }
}
__device__ inline double waveSumD(double v) {
#pragma unroll
  for (int o = 32; o >= 1; o >>= 1) v += __shfl_xor(v, o, 64);
  return v;
}

// Kernel 1: 1024 blocks x 256 threads; block owns (batch b, 2 hyps).
// Phase 1 (redundant per block, bitwise-identical across blocks of a batch):
//   f64 2x2 solve per hyp + batch stats (ddof=1, two-pass) + one-sided z>2
//   outlier replacement, all in LDS/registers — no global hyp tables.
// Phase 2: votes for the block's 2 hyps. float4 pixel loads (96%4==0 keeps a
//   group in one row). Vote test yy*u + yx*v > y*u + x*v — the reference's
//   normalization is sign-preserving and NaN compares false either way.
// Tail: t==0 folds the block's 2 hyps into 3 f64 partials {w, py*w, px*w}
//   and plain-stores them to the block's OWN slot. No atomics, no fences, no
//   tickets — cross-block communication through the kernel-boundary release
//   (R2/R3/R5 showed every in-kernel completion scheme loses 9-30 µs).
__global__ __launch_bounds__(256, 4)
void vote_kernel(const float* __restrict__ uv, const int* __restrict__ pair,
                 double* __restrict__ partials /* [BATCH][3][GPB] */) {
  __shared__ double sPy[NHYP], sPx[NHYP];
  __shared__ float sWm[NHYP];
  __shared__ int sNan[NHYP];
  __shared__ double sh[2][2];
  __shared__ int sC[4][2];

  const int t = threadIdx.x;
  const int lane = t & 63;
  const int wv = t >> 6;
  const int b = blockIdx.x >> 6;         // / GPB
  const int g = blockIdx.x & (GPB - 1);
  const float* uvb = uv + (size_t)b * 2 * NP;

  // ---- phase 1: solves (threads 0..127) ----
  double Yy = 0.0, Yx = 0.0;
  if (t < NHYP) {
    int i0 = pair[(b * NHYP + t) * 2 + 0];
    int i1 = pair[(b * NHYP + t) * 2 + 1];
    double u0 = uvb[i0], v0 = uvb[NP + i0];
    double u1 = uvb[i1], v1 = uvb[NP + i1];
    double y0 = (double)(i0 / Ww), x0 = (double)(i0 % Ww);
    double y1 = (double)(i1 / Ww), x1 = (double)(i1 % Ww);
    // A = [[u0,-u1],[v0,-v1]], Bvec = [y1-y0, x1-x0]; s = (A^-1 Bvec).x
    double det = u1 * v0 - u0 * v1;
    double s = (u1 * (x1 - x0) - v1 * (y1 - y0)) / det;
    Yy = s * u0 + y0;
    Yx = s * v0 + x0;
  }
  double sy = Yy, sx = Yx;
  waveSum2D(sy, sx);                     // waves 2,3 shuffle zeros: harmless
  if (lane == 0 && wv < 2) { sh[wv][0] = sy; sh[wv][1] = sx; }
  __syncthreads();
  const double my = (sh[0][0] + sh[1][0]) * (1.0 / NHYP);
  const double mx = (sh[0][1] + sh[1][1]) * (1.0 / NHYP);
  const double dy = Yy - my, dx = Yx - mx;
  double qy = dy * dy, qx = dx * dx;
  waveSum2D(qy, qx);
  __syncthreads();
  if (lane == 0 && wv < 2) { sh[wv][0] = qy; sh[wv][1] = qx; }
  __syncthreads();
  if (t < NHYP) {
    double vy = (sh[0][0] + sh[1][0]) * (1.0 / (NHYP - 1));
    double vx = (sh[0][1] + sh[1][1]) * (1.0 / (NHYP - 1));
    // dy/sqrt(vy) > 2  <=>  dy > 2*sqrt(vy)  (incl. 0/0->NaN->false, +inf)
    bool outl = (dy > 2.0 * sqrt(vy)) || (dx > 2.0 * sqrt(vx));
    double py = outl ? my : Yy;
    double px = outl ? mx : Yx;
    sPy[t] = py;
    sPx[t] = px;
    // h_in_mask==1 <=> trunc(Yp) hits a lattice point <=> Yp in (-1,96)^2
    sWm[t] = (py > -1.0 && py < 96.0 && px > -1.0 && px < 96.0) ? 10.0f : 1.0f;
    sNan[t] = (isnan(py) || isnan(px)) ? 1 : 0;
  }
  __syncthreads();

  // ---- phase 2: votes for hyps h0, h1 ----
  const int h0 = g * HPB, h1 = h0 + 1;
  const float yy0 = (float)sPy[h0], yx0 = (float)sPx[h0];
  const float yy1 = (float)sPy[h1], yx1 = (float)sPx[h1];
  int c0 = 0, c1 = 0;
#pragma unroll
  for (int it = 0; it < 9; ++it) {
    const int p = (it * 256 + t) * 4;
    const float4 u4 = *(const float4*)(uvb + p);
    const float4 v4 = *(const float4*)(uvb + NP + p);
    const int yi = p / Ww;
    const float fy = (float)yi;
    const float fx = (float)(p - yi * Ww);
    const float k0 = fy * u4.x + fx * v4.x;
    const float k1 = fy * u4.y + (fx + 1.0f) * v4.y;
    const float k2 = fy * u4.z + (fx + 2.0f) * v4.z;
    const float k3 = fy * u4.w + (fx + 3.0f) * v4.w;
    c0 += (fmaf(yy0, u4.x, yx0 * v4.x) > k0) ? 1 : 0;
    c0 += (fmaf(yy0, u4.y, yx0 * v4.y) > k1) ? 1 : 0;
    c0 += (fmaf(yy0, u4.z, yx0 * v4.z) > k2) ? 1 : 0;
    c0 += (fmaf(yy0, u4.w, yx0 * v4.w) > k3) ? 1 : 0;
    c1 += (fmaf(yy1, u4.x, yx1 * v4.x) > k0) ? 1 : 0;
    c1 += (fmaf(yy1, u4.y, yx1 * v4.y) > k1) ? 1 : 0;
    c1 += (fmaf(yy1, u4.z, yx1 * v4.z) > k2) ? 1 : 0;
    c1 += (fmaf(yy1, u4.w, yx1 * v4.w) > k3) ? 1 : 0;
  }
  waveSum2I(c0, c1);
  if (lane == 0) { sC[wv][0] = c0; sC[wv][1] = c1; }
  __syncthreads();

  // ---- tail: fold 2 hyps -> 3 partials, plain store to own slot ----
  if (t == 0) {
    int cnt0 = sC[0][0] + sC[1][0] + sC[2][0] + sC[3][0];
    int cnt1 = sC[0][1] + sC[1][1] + sC[2][1] + sC[3][1];
    double w0 = sNan[h0] ? 0.0 : (double)cnt0 * (double)sWm[h0];
    double w1 = sNan[h1] ? 0.0 : (double)cnt1 * (double)sWm[h1];
    double ny = (sNan[h0] ? 0.0 : sPy[h0] * w0) +
                (sNan[h1] ? 0.0 : sPy[h1] * w1);
    double nx = (sNan[h0] ? 0.0 : sPx[h0] * w0) +
                (sNan[h1] ? 0.0 : sPx[h1] * w1);
    double* slot = partials + (size_t)b * 3 * GPB;
    slot[0 * GPB + g] = w0 + w1;
    slot[1 * GPB + g] = ny;
    slot[2 * GPB + g] = nx;
  }
}

// Kernel 2: 16 blocks x 192 threads (3 waves: w, ny, nx). Deterministic
// fixed-order reduce of the 64 slots; divide once; write out[, ::-1].
__global__ __launch_bounds__(192)
void final_kernel(const double* __restrict__ partials,
                  float* __restrict__ out) {
  __shared__ double sD[3];
  const int t = threadIdx.x;
  const int lane = t & 63;
  const int wv = t >> 6;
  const int b = blockIdx.x;

  double val = partials[((size_t)b * 3 + wv) * GPB + lane];
  val = waveSumD(val);
  if (lane == 0) sD[wv] = val;
  __syncthreads();
  if (t == 0) {
    double wsum = sD[0];
    out[b * 2 + 0] = (float)(sD[2] / wsum);   // weighted_mean[:, ::-1]
    out[b * 2 + 1] = (float)(sD[1] / wsum);
  }
}

}  // namespace

extern "C" void kernel_launch(void* const* d_in, const int* in_sizes, int n_in,
                              void* d_out, int out_size, void* d_ws, size_t ws_size,
                              hipStream_t stream) {
  const float* uv = (const float*)d_in[0];   // (16,2,96,96) f32
  // d_in[1] = mask, unused (all ones; never read by the reference math)
  const int* pair = (const int*)d_in[2];     // (16,128,2) i32
  float* out = (float*)d_out;                // (16,2) f32

  double* partials = (double*)d_ws;          // 16*3*64*8 = 24576 B

  vote_kernel<<<BATCH * GPB, 256, 0, stream>>>(uv, pair, partials);
  final_kernel<<<BATCH, 192, 0, stream>>>(partials, out);
}